// Round 7
// baseline (546.753 us; speedup 1.0000x reference)
//
#include <hip/hip_runtime.h>

// ---------------------------------------------------------------------------
// Actor: GRU over V=20 vehicle slots (H=256) + MLP head 271->1024->1024->512->256->1
// B=16384, F=15. All GEMMs in bf16 MFMA (16x16x32), fp32 accumulate.
//
// Round-21: allocator law established over r15-r20: arch-VGPR cap =
// 65536/wg_size (1024->64, 512->128, 256->256); residency needs
// (arch+accum)x(waves/SIMD) <= 512. Weight-load law: per-CU loads/step =
// 432 x (64/rows_per_block) regardless of wave count -> 64-row blocks are
// mandatory. Only config fitting {64 rows, merged-pass ~180 regs, no spill}:
// wg=256 (4 waves x 64 cols as runtime jt=4 slices, nt=4), grid 256.
// Merged single-pass (one shared h-read feeds all 3 gate MFMAs, no rzbuf,
// fused epilogue, LDS h_old) -- r19's verified structure re-tiled. 432
// MFMA/wave-step, 12 indep acc chains, ~240 spare regs for prefetch depth.
// ---------------------------------------------------------------------------

typedef __attribute__((ext_vector_type(8))) __bf16 bf16x8;
typedef __attribute__((ext_vector_type(4))) __bf16 bf16x4;
typedef __attribute__((ext_vector_type(4))) float  floatx4;

#define MFMA16(a, b, c) __builtin_amdgcn_mfma_f32_16x16x32_bf16((a), (b), (c), 0, 0, 0)

#define GL_LDS16(g, l)                                                         \
    __builtin_amdgcn_global_load_lds(                                          \
        (const __attribute__((address_space(1))) void*)(g),                    \
        (__attribute__((address_space(3))) void*)(l), 16, 0, 0)

__device__ __forceinline__ float sigmoid_f(float x) { return 1.f / (1.f + __expf(-x)); }
__device__ __forceinline__ float tanh_f(float x)    { return 1.f - 2.f / (1.f + __expf(2.f * x)); }

// ---------------------------------------------------------------------------
// Weight prep:
//   Wg1  [512][288]  rows g in {r(0..255), z(256..511)}:
//        [W_ih[g][0..14] | bsum[g] | 0 x16 | W_hh[g][0..255]]   (col 15 = bias)
//   W1p  [1024][288] : [W1[o][0..14] | 0 x17 | W1[o][15..270]]
//   W2b  [1024][1024], W3b [512][1024], W4b [256][512]  : direct cvt
//   Win_n[256][32]   : [W_ih[512+j][0..14] | b_ih[512+j] | 0 x16] (col 15 = bias)
//   Whh_n[256][256]  : W_hh rows 512..767
//   bhhn [256] = b_hh[512+]
// ---------------------------------------------------------------------------
#define S0 147456u
#define S1 442368u
#define S2 1490944u
#define S3 2015232u
#define S4 2146304u
#define S5 2154496u
#define S6 2220032u
#define S7 2220544u
#define S8 2221056u

__global__ void prep_kernel(const float* __restrict__ W_ih, const float* __restrict__ W_hh,
                            const float* __restrict__ b_ih, const float* __restrict__ b_hh,
                            const float* __restrict__ W1, const float* __restrict__ W2,
                            const float* __restrict__ W3, const float* __restrict__ W4,
                            __bf16* __restrict__ Wg1, __bf16* __restrict__ W1p,
                            __bf16* __restrict__ W2b, __bf16* __restrict__ W3b,
                            __bf16* __restrict__ W4b, __bf16* __restrict__ Win_n,
                            __bf16* __restrict__ Whh_n, float* __restrict__ bsum,
                            float* __restrict__ bihn, float* __restrict__ bhhn)
{
    for (unsigned i = blockIdx.x * blockDim.x + threadIdx.x; i < S8; i += gridDim.x * blockDim.x) {
        if (i < S0) {
            unsigned g = i / 288u, c = i % 288u;
            float v;
            if (c < 15u)       v = W_ih[g * 15u + c];
            else if (c == 15u) v = b_ih[g] + b_hh[g];          // folded r/z bias
            else if (c < 32u)  v = 0.f;
            else               v = W_hh[g * 256u + (c - 32u)];
            Wg1[i] = (__bf16)v;
        } else if (i < S1) {
            unsigned t = i - S0, o = t / 288u, c = t % 288u;
            float v = (c < 15u) ? W1[o * 271u + c] : ((c < 32u) ? 0.f : W1[o * 271u + (c - 17u)]);
            W1p[t] = (__bf16)v;
        } else if (i < S2) {
            unsigned t = i - S1; W2b[t] = (__bf16)W2[t];
        } else if (i < S3) {
            unsigned t = i - S2; W3b[t] = (__bf16)W3[t];
        } else if (i < S4) {
            unsigned t = i - S3; W4b[t] = (__bf16)W4[t];
        } else if (i < S5) {
            unsigned t = i - S4, j = t / 32u, c = t % 32u;
            float v;
            if (c < 15u)       v = W_ih[(512u + j) * 15u + c];
            else if (c == 15u) v = b_ih[512u + j];             // folded xn bias
            else               v = 0.f;
            Win_n[t] = (__bf16)v;
        } else if (i < S6) {
            unsigned t = i - S5; Whh_n[t] = (__bf16)W_hh[512u * 256u + t];
        } else if (i < S7) {
            unsigned t = i - S6; bsum[t] = b_ih[t] + b_hh[t];
        } else {
            unsigned t = i - S7;
            if (t < 256u) bihn[t] = b_ih[512u + t];
            else          bhhn[t - 256u] = b_hh[512u + t - 256u];
        }
    }
}

// ---------------------------------------------------------------------------
// GRU kernel (r21). 256 blocks x 256 threads (4 waves). 64 batch rows/block.
// Wave w owns gate cols w*64..w*64+63 as a RUNTIME loop over 4 j-tiles.
// Per step, per jt: accumulate {ar, az, ah} over the h tile (ONE shared
// h-fragment b128 read per (kk,nt) feeds all 3 gate MFMAs), {ar, az, ax}
// over the state slab, then the fused epilogue: r,z sigmoid (fp32 in regs),
// n = tanh(ax + r*(ah+bhn)), h' = (1-z)n + z*h_old (h_old read from LDS
// buffer SB at the write slot). hbuf double-buffered, 1 barrier/step.
// sbuf stride 40: conflict-free. wg=256 -> arch-VGPR cap 256 (no spill).
// ---------------------------------------------------------------------------
#define HSTRIDE 264
#define HBUF_N  (64 * HSTRIDE)    // 16896
#define SSTRIDE 40
#define SBUF_N  (64 * SSTRIDE)    // 2560 per buffer

__global__ __launch_bounds__(256)
void gru_kernel(const float* __restrict__ state,
                const __bf16* __restrict__ Wg1,  const __bf16* __restrict__ Win_n,
                const __bf16* __restrict__ Whh_n,
                const float* __restrict__ bhhn, __bf16* __restrict__ x0)
{
    __shared__ __bf16 hbuf[2 * HBUF_N];        // 67584 B
    __shared__ __bf16 sbuf[2 * SBUF_N];        // 10240 B; k 16..39 zero, k15 = 1.0

    const int tid  = threadIdx.x;
    const int wave = tid >> 6;    // 0..3 : 64-col group
    const int lane = tid & 63;
    const int q    = lane >> 4;
    const int ln   = lane & 15;
    const int b0   = blockIdx.x * 64;

    {   // zero h buffer 0 and both sbuf buffers
        bf16x8 z = {};
        bf16x8* p = (bf16x8*)hbuf;
        #pragma unroll
        for (int t = 0; t < 9; t++) {
            int i = tid + t * 256;
            if (i < HBUF_N / 8) p[i] = z;
        }
        #pragma unroll
        for (int t = 0; t < 3; t++) {
            int i = tid + t * 256;
            if (i < 2 * SBUF_N / 8) ((bf16x8*)sbuf)[i] = z;
        }
    }
    const int srow = tid >> 4, sk = tid & 15;   // 16 rows x 16 cols; 4 row-passes

    const __bf16* hread  = hbuf + ln * HSTRIDE + q * 8;              // + nt*16*HSTRIDE
    __bf16*       hwrite = hbuf + ln * HSTRIDE + wave * 64 + q * 4;  // + jt*16 + nt*16*HSTRIDE
    const __bf16* sread  = sbuf + ln * SSTRIDE + q * 8;              // + nt*16*SSTRIDE

    // stage state slice v=0, then set the permanent 1.0 bias column (k=15)
    if (sk < 15) {
        #pragma unroll
        for (int t = 0; t < 4; t++)
            sbuf[(srow + t * 16) * SSTRIDE + sk] =
                (__bf16)state[(size_t)(b0 + srow + t * 16) * 300 + sk];
    }
    if (tid < 128) sbuf[(tid >> 6) * SBUF_N + (tid & 63) * SSTRIDE + 15] = (__bf16)1.0f;
    __syncthreads();

#define GRU_STEP(v, SB)                                                          \
    {                                                                            \
        float sn[4] = {0.f, 0.f, 0.f, 0.f};                                      \
        if ((v) < 19 && sk < 15) {                                               \
            _Pragma("unroll")                                                    \
            for (int t = 0; t < 4; t++)                                          \
                sn[t] = state[(size_t)(b0 + srow + t * 16) * 300 +               \
                              ((v) + 1) * 15 + sk];                              \
        }                                                                        \
        const floatx4 zf = {0.f, 0.f, 0.f, 0.f};                                 \
        _Pragma("unroll 1")                                                      \
        for (int jt = 0; jt < 4; ++jt) {                                         \
            const unsigned jr = (unsigned)(wave * 64 + jt * 16 + ln);            \
            const __bf16* wr = Wg1   + jr * 288u + q * 8u;                       \
            const __bf16* wz = wr + 256u * 288u;                                 \
            const __bf16* wh = Whh_n + jr * 256u + q * 8u;                       \
            const __bf16* wx = Win_n + jr * 32u  + q * 8u;                       \
            floatx4 ar[4], az[4], ah[4], ax[4];                                  \
            _Pragma("unroll")                                                    \
            for (int nt = 0; nt < 4; nt++) { ar[nt]=zf; az[nt]=zf; ah[nt]=zf; }  \
            _Pragma("unroll")                                                    \
            for (int kk = 0; kk < 8; ++kk) {                                     \
                bf16x8 a0 = *(const bf16x8*)(wr + 32 + kk * 32);                 \
                bf16x8 a1 = *(const bf16x8*)(wz + 32 + kk * 32);                 \
                bf16x8 a2 = *(const bf16x8*)(wh + kk * 32);                      \
                _Pragma("unroll")                                                \
                for (int nt = 0; nt < 4; nt++) {                                 \
                    bf16x8 b = *(const bf16x8*)(hread + (SB) * HBUF_N +          \
                                                nt * (16 * HSTRIDE) + kk * 32);  \
                    ar[nt] = MFMA16(a0, b, ar[nt]);                              \
                    az[nt] = MFMA16(a1, b, az[nt]);                              \
                    ah[nt] = MFMA16(a2, b, ah[nt]);                              \
                }                                                                \
            }                                                                    \
            {                                                                    \
                bf16x8 a0 = *(const bf16x8*)(wr);                                \
                bf16x8 a1 = *(const bf16x8*)(wz);                                \
                bf16x8 a2 = *(const bf16x8*)(wx);                                \
                _Pragma("unroll")                                                \
                for (int nt = 0; nt < 4; nt++) {                                 \
                    bf16x8 b = *(const bf16x8*)(sread + (SB) * SBUF_N +          \
                                                nt * (16 * SSTRIDE));            \
                    ar[nt] = MFMA16(a0, b, ar[nt]);                              \
                    az[nt] = MFMA16(a1, b, az[nt]);                              \
                    ax[nt] = MFMA16(a2, b, zf);                                  \
                }                                                                \
            }                                                                    \
            const floatx4 Bhn =                                                  \
                *(const floatx4*)(bhhn + wave * 64 + jt * 16 + q * 4);           \
            _Pragma("unroll")                                                    \
            for (int nt = 0; nt < 4; nt++) {                                     \
                bf16x4 ho = *(const bf16x4*)(hwrite + jt * 16 + (SB) * HBUF_N +  \
                                             nt * (16 * HSTRIDE));               \
                bf16x4 hv;                                                       \
                _Pragma("unroll")                                                \
                for (int r = 0; r < 4; r++) {                                    \
                    float rg = sigmoid_f(ar[nt][r]);                             \
                    float zg = sigmoid_f(az[nt][r]);                             \
                    float nn = tanh_f(ax[nt][r] + rg * (ah[nt][r] + Bhn[r]));    \
                    hv[r] = (__bf16)((1.f - zg) * nn + zg * (float)ho[r]);       \
                }                                                                \
                *(bf16x4*)(hwrite + jt * 16 + (1 - (SB)) * HBUF_N +              \
                           nt * (16 * HSTRIDE)) = hv;                            \
            }                                                                    \
        }                                                                        \
        if ((v) < 19 && sk < 15) {                                               \
            _Pragma("unroll")                                                    \
            for (int t = 0; t < 4; t++)                                          \
                sbuf[(1 - (SB)) * SBUF_N + (srow + t * 16) * SSTRIDE + sk] =     \
                    (__bf16)sn[t];                                               \
        }                                                                        \
        __syncthreads();                                                         \
    }

    #pragma unroll 1
    for (int v2 = 0; v2 < 10; ++v2) {
        GRU_STEP(2 * v2,     0)
        GRU_STEP(2 * v2 + 1, 1)
    }
#undef GRU_STEP

    // ---- epilogue: final h is in hbuf buffer 0 (step 19 wrote 1-SB = 0) ----
    // x0 = [state[:,0,:] (15) | 0-pad to 32 | h (256)], coalesced b128 moves.
    {
        const int erow = tid >> 2, p = tid & 3;    // 64 rows x 4 segs
        #pragma unroll
        for (int s = 0; s < 8; s++) {
            const int col = p * 8 + s * 32;
            *(bf16x8*)(x0 + (size_t)(b0 + erow) * 288 + 32 + col) =
                *(const bf16x8*)(hbuf + erow * HSTRIDE + col);
        }
    }
    #pragma unroll
    for (int t = 0; t < 8; t++) {
        int i = tid + t * 256;
        int erow = i >> 5, c = i & 31;
        float s = (c < 15) ? state[(size_t)(b0 + erow) * 300 + c] : 0.f;
        x0[(size_t)(b0 + erow) * 288 + c] = (__bf16)s;
    }
}

// ---------------------------------------------------------------------------
// LDS-staged GEMM, BK=64: C = act(A[M][K] @ W[N][K]^T + bias), bf16.
// 256 thr (4 waves 2x2), tile 128x128. Staging: 8 global_load_lds(16B)
// rounds per 64-k slab (two 32-k halves), ONE barrier pair per slab. K tail
// of 32 supported (gemm1 K=288). LDS: staging 32 KB inside the bounce union.
// ---------------------------------------------------------------------------
__global__ __launch_bounds__(256)
void gemm_bias_act(const __bf16* __restrict__ A, const __bf16* __restrict__ W,
                   const float* __restrict__ bias, __bf16* __restrict__ C,
                   int N, int K, int relu)
{
    __shared__ __bf16 smem[128 * 136];           // 34816 B
    // staging layout: A-lo [128][32] @0, A-hi @4096, B-lo @8192, B-hi @12288

    const int tid  = threadIdx.x;
    const int wave = tid >> 6, lane = tid & 63;
    const int q = lane >> 4, ln = lane & 15;
    const int wm = wave >> 1, wn = wave & 1;
    const int arow0 = blockIdx.x * 128;
    const int bcol0 = blockIdx.y * 128;

    float bv[4];
    #pragma unroll
    for (int n = 0; n < 4; n++) bv[n] = bias[bcol0 + wn * 64 + n * 16 + ln];

    floatx4 acc[4][4];
    const floatx4 zf = {0.f, 0.f, 0.f, 0.f};
    #pragma unroll
    for (int m = 0; m < 4; m++)
        #pragma unroll
        for (int n = 0; n < 4; n++) acc[m][n] = zf;

    const int stg_row = wave * 16 + (lane >> 2);   // + rd*64
    const int stg_k   = (lane & 3) * 8;            // + h*32
    const int lds_off = wave * 512;                // + rd*2048, + h*4096

    int kt = 0;
    for (; kt + 64 <= K; kt += 64) {
        #pragma unroll
        for (int h = 0; h < 2; h++)
            #pragma unroll
            for (int rd = 0; rd < 2; rd++) {
                GL_LDS16(A + (size_t)(arow0 + stg_row + rd * 64) * K + kt + h * 32 + stg_k,
                         smem + h * 4096 + lds_off + rd * 2048);
                GL_LDS16(W + (size_t)(bcol0 + stg_row + rd * 64) * K + kt + h * 32 + stg_k,
                         smem + 8192 + h * 4096 + lds_off + rd * 2048);
            }
        __syncthreads();
        #pragma unroll
        for (int h = 0; h < 2; h++) {
            bf16x8 af[4], bf[4];
            #pragma unroll
            for (int m = 0; m < 4; m++)
                af[m] = *(const bf16x8*)(smem + h * 4096 + (wm * 64 + m * 16 + ln) * 32 + q * 8);
            #pragma unroll
            for (int n = 0; n < 4; n++)
                bf[n] = *(const bf16x8*)(smem + 8192 + h * 4096 + (wn * 64 + n * 16 + ln) * 32 + q * 8);
            #pragma unroll
            for (int n = 0; n < 4; n++)
                #pragma unroll
                for (int m = 0; m < 4; m++)
                    acc[m][n] = MFMA16(af[m], bf[n], acc[m][n]);
        }
        __syncthreads();
    }
    if (kt < K) {   // 32-k tail
        #pragma unroll
        for (int rd = 0; rd < 2; rd++) {
            GL_LDS16(A + (size_t)(arow0 + stg_row + rd * 64) * K + kt + stg_k,
                     smem + lds_off + rd * 2048);
            GL_LDS16(W + (size_t)(bcol0 + stg_row + rd * 64) * K + kt + stg_k,
                     smem + 8192 + lds_off + rd * 2048);
        }
        __syncthreads();
        bf16x8 af[4], bf[4];
        #pragma unroll
        for (int m = 0; m < 4; m++)
            af[m] = *(const bf16x8*)(smem + (wm * 64 + m * 16 + ln) * 32 + q * 8);
        #pragma unroll
        for (int n = 0; n < 4; n++)
            bf[n] = *(const bf16x8*)(smem + 8192 + (wn * 64 + n * 16 + ln) * 32 + q * 8);
        #pragma unroll
        for (int n = 0; n < 4; n++)
            #pragma unroll
            for (int m = 0; m < 4; m++)
                acc[m][n] = MFMA16(af[m], bf[n], acc[m][n]);
        __syncthreads();
    }

    // epilogue: bias+act -> LDS bounce (stride 136) -> coalesced b128 stores
    #pragma unroll
    for (int m = 0; m < 4; m++)
        #pragma unroll
        for (int n = 0; n < 4; n++)
            #pragma unroll
            for (int r = 0; r < 4; r++) {
                float val = acc[m][n][r] + bv[n];
                if (relu) val = fmaxf(val, 0.f);
                smem[(wm * 64 + m * 16 + q * 4 + r) * 136 + wn * 64 + n * 16 + ln] = (__bf16)val;
            }
    __syncthreads();
    {
        const int row = tid >> 4, seg = tid & 15;
        #pragma unroll
        for (int p = 0; p < 8; p++) {
            const int rr = row + p * 16;
            *(bf16x8*)(C + (size_t)(arow0 + rr) * N + bcol0 + seg * 8) =
                *(const bf16x8*)(smem + rr * 136 + seg * 8);
        }
    }
}

// ---------------------------------------------------------------------------
// Head: out[b] = tanh(dot(x4[b][0..255], Wp) + bp).  4 lanes per row.
// ---------------------------------------------------------------------------
__global__ __launch_bounds__(256)
void head_kernel(const __bf16* __restrict__ x4, const float* __restrict__ Wp,
                 const float* __restrict__ bp, float* __restrict__ out)
{
    const int tid = threadIdx.x;
    const int wave = tid >> 6, lane = tid & 63;
    const int row = blockIdx.x * 64 + wave * 16 + (lane >> 2);
    const int part = lane & 3;
    const __bf16* xp = x4 + (size_t)row * 256 + part * 64;
    const float* wp = Wp + part * 64;
    float sum = 0.f;
    #pragma unroll
    for (int i = 0; i < 8; i++) {
        bf16x8 xv = *(const bf16x8*)(xp + i * 8);
        #pragma unroll
        for (int jj = 0; jj < 8; jj++) sum += (float)xv[jj] * wp[i * 8 + jj];
    }
    sum += __shfl_xor(sum, 1);
    sum += __shfl_xor(sum, 2);
    if (part == 0) out[row] = tanhf(sum + bp[0]);
}

// ---------------------------------------------------------------------------
extern "C" void kernel_launch(void* const* d_in, const int* in_sizes, int n_in,
                              void* d_out, int out_size, void* d_ws, size_t ws_size,
                              hipStream_t stream)
{
    const float* state = (const float*)d_in[0];
    const float* W_ih  = (const float*)d_in[1];
    const float* W_hh  = (const float*)d_in[2];
    const float* b_ih  = (const float*)d_in[3];
    const float* b_hh  = (const float*)d_in[4];
    const float* W1    = (const float*)d_in[5];
    const float* b1    = (const float*)d_in[6];
    const float* W2    = (const float*)d_in[7];
    const float* b2    = (const float*)d_in[8];
    const float* W3    = (const float*)d_in[9];
    const float* b3    = (const float*)d_in[10];
    const float* W4    = (const float*)d_in[11];
    const float* b4    = (const float*)d_in[12];
    const float* Wp    = (const float*)d_in[13];
    const float* bp    = (const float*)d_in[14];
    float* out = (float*)d_out;

    char* ws = (char*)d_ws;
    size_t off = 0;
    auto alloc = [&](size_t bytes) -> void* {
        void* p = ws + off;
        off += (bytes + 255) & ~(size_t)255;
        return p;
    };
    __bf16* Wg1   = (__bf16*)alloc(512 * 288 * 2);
    __bf16* W1p   = (__bf16*)alloc(1024 * 288 * 2);
    __bf16* W2b   = (__bf16*)alloc(1024 * 1024 * 2);
    __bf16* W3b   = (__bf16*)alloc(512 * 1024 * 2);
    __bf16* W4b   = (__bf16*)alloc(256 * 512 * 2);
    __bf16* Win_n = (__bf16*)alloc(256 * 32 * 2);
    __bf16* Whh_n = (__bf16*)alloc(256 * 256 * 2);
    float*  bsum  = (float*)alloc(512 * 4);
    float*  bihn  = (float*)alloc(256 * 4);
    float*  bhhn  = (float*)alloc(256 * 4);
    __bf16* x0    = (__bf16*)alloc((size_t)16384 * 288 * 2);
    __bf16* xA    = (__bf16*)alloc((size_t)16384 * 1024 * 2);
    __bf16* xB    = (__bf16*)alloc((size_t)16384 * 1024 * 2);

    prep_kernel<<<2048, 256, 0, stream>>>(W_ih, W_hh, b_ih, b_hh, W1, W2, W3, W4,
                                          Wg1, W1p, W2b, W3b, W4b, Win_n, Whh_n,
                                          bsum, bihn, bhhn);
    gru_kernel<<<256, 256, 0, stream>>>(state, Wg1, Win_n, Whh_n, bhhn, x0);
    gemm_bias_act<<<dim3(128, 8), 256, 0, stream>>>(x0, W1p, b1, xA, 1024, 288, 1);
    gemm_bias_act<<<dim3(128, 8), 256, 0, stream>>>(xA, W2b, b2, xB, 1024, 1024, 1);
    gemm_bias_act<<<dim3(128, 4), 256, 0, stream>>>(xB, W3b, b3, xA, 512, 1024, 1);
    gemm_bias_act<<<dim3(128, 2), 256, 0, stream>>>(xA, W4b, b4, xB, 256, 512, 1);
    head_kernel<<<256, 256, 0, stream>>>(xB, Wp, bp, out);
}

// Round 8
// 460.602 us; speedup vs baseline: 1.1870x; 1.1870x over previous
//
#include <hip/hip_runtime.h>

// ---------------------------------------------------------------------------
// Actor: GRU over V=20 vehicle slots (H=256) + MLP head 271->1024->1024->512->256->1
// B=16384, F=15. All GEMMs in bf16 MFMA (16x16x32), fp32 accumulate.
//
// Round-22: REVERT to the round-0 baseline (best harness-verified: 456.9 us
// prior session / 464.1 us round-0 re-bench; GRU 292 us). Rounds 15-21
// falsified the merged-single-pass family: its LDS win (bank conflicts
// 2.49e7 -> 1.2e7) is strictly dominated by occupancy losses under the
// allocator laws measured this session:
//   - arch-VGPR cap = 65536/workgroup_size (1024->64, 512->128, 256->256)
//   - co-residency needs (arch+accum) x waves/SIMD <= 512 (exact-full never
//     pairs: r17's 2x8x128 = 512/SIMD failed)
//   - per-CU L2 weight traffic = 432 frags x (64/rows_per_block)/step ->
//     64-row blocks mandatory; grid 256 = 1 block/CU caps wg-256 at 1
//     wave/SIMD (r21, latency-bound)
// r11's two-pass structure is the unique config satisfying all three:
// wg-1024 (16 waves, 46% occ), 64 VGPR (no spill), 64-row blocks, with the
// rzbuf bf16 bounce keeping per-pass accum liveness at 32 VGPRs.
// ---------------------------------------------------------------------------

typedef __attribute__((ext_vector_type(8))) __bf16 bf16x8;
typedef __attribute__((ext_vector_type(4))) __bf16 bf16x4;
typedef __attribute__((ext_vector_type(4))) float  floatx4;

#define MFMA16(a, b, c) __builtin_amdgcn_mfma_f32_16x16x32_bf16((a), (b), (c), 0, 0, 0)

#define GL_LDS16(g, l)                                                         \
    __builtin_amdgcn_global_load_lds(                                          \
        (const __attribute__((address_space(1))) void*)(g),                    \
        (__attribute__((address_space(3))) void*)(l), 16, 0, 0)

__device__ __forceinline__ float sigmoid_f(float x) { return 1.f / (1.f + __expf(-x)); }
__device__ __forceinline__ float tanh_f(float x)    { return 1.f - 2.f / (1.f + __expf(2.f * x)); }

// ---------------------------------------------------------------------------
// Weight prep:
//   Wg1  [512][288]  rows g in {r(0..255), z(256..511)}:
//        [W_ih[g][0..14] | bsum[g] | 0 x16 | W_hh[g][0..255]]   (col 15 = bias)
//   W1p  [1024][288] : [W1[o][0..14] | 0 x17 | W1[o][15..270]]
//   W2b  [1024][1024], W3b [512][1024], W4b [256][512]  : direct cvt
//   Win_n[256][32]   : [W_ih[512+j][0..14] | b_ih[512+j] | 0 x16] (col 15 = bias)
//   Whh_n[256][256]  : W_hh rows 512..767
//   bhhn [256] = b_hh[512+]
// ---------------------------------------------------------------------------
#define S0 147456u
#define S1 442368u
#define S2 1490944u
#define S3 2015232u
#define S4 2146304u
#define S5 2154496u
#define S6 2220032u
#define S7 2220544u
#define S8 2221056u

__global__ void prep_kernel(const float* __restrict__ W_ih, const float* __restrict__ W_hh,
                            const float* __restrict__ b_ih, const float* __restrict__ b_hh,
                            const float* __restrict__ W1, const float* __restrict__ W2,
                            const float* __restrict__ W3, const float* __restrict__ W4,
                            __bf16* __restrict__ Wg1, __bf16* __restrict__ W1p,
                            __bf16* __restrict__ W2b, __bf16* __restrict__ W3b,
                            __bf16* __restrict__ W4b, __bf16* __restrict__ Win_n,
                            __bf16* __restrict__ Whh_n, float* __restrict__ bsum,
                            float* __restrict__ bihn, float* __restrict__ bhhn)
{
    for (unsigned i = blockIdx.x * blockDim.x + threadIdx.x; i < S8; i += gridDim.x * blockDim.x) {
        if (i < S0) {
            unsigned g = i / 288u, c = i % 288u;
            float v;
            if (c < 15u)       v = W_ih[g * 15u + c];
            else if (c == 15u) v = b_ih[g] + b_hh[g];          // folded r/z bias
            else if (c < 32u)  v = 0.f;
            else               v = W_hh[g * 256u + (c - 32u)];
            Wg1[i] = (__bf16)v;
        } else if (i < S1) {
            unsigned t = i - S0, o = t / 288u, c = t % 288u;
            float v = (c < 15u) ? W1[o * 271u + c] : ((c < 32u) ? 0.f : W1[o * 271u + (c - 17u)]);
            W1p[t] = (__bf16)v;
        } else if (i < S2) {
            unsigned t = i - S1; W2b[t] = (__bf16)W2[t];
        } else if (i < S3) {
            unsigned t = i - S2; W3b[t] = (__bf16)W3[t];
        } else if (i < S4) {
            unsigned t = i - S3; W4b[t] = (__bf16)W4[t];
        } else if (i < S5) {
            unsigned t = i - S4, j = t / 32u, c = t % 32u;
            float v;
            if (c < 15u)       v = W_ih[(512u + j) * 15u + c];
            else if (c == 15u) v = b_ih[512u + j];             // folded xn bias
            else               v = 0.f;
            Win_n[t] = (__bf16)v;
        } else if (i < S6) {
            unsigned t = i - S5; Whh_n[t] = (__bf16)W_hh[512u * 256u + t];
        } else if (i < S7) {
            unsigned t = i - S6; bsum[t] = b_ih[t] + b_hh[t];
        } else {
            unsigned t = i - S7;
            if (t < 256u) bihn[t] = b_ih[512u + t];
            else          bhhn[t - 256u] = b_hh[512u + t - 256u];
        }
    }
}

// ---------------------------------------------------------------------------
// GRU kernel (r11). 256 blocks x 1024 threads (16 waves). 64 batch rows/block.
// Wave w owns gate cols w*16..w*16+15. Per step, 2 unroll-1 passes:
//   p0: acc (ar,az) over all 4 nt (32 regs) -> sigmoid -> rzbuf[nt][tid]
//   p1: acc (axn,ahn) (32 regs) -> n=tanh(axn+r*(ahn+bhn)), h'=(1-z)n+z*h_old
// hbuf[2][64][264] double-buffered, 1 barrier/step. sbuf stride 40:
// 5*ln+q mod 8 covers all 8 bank groups -> conflict-free state reads.
// ---------------------------------------------------------------------------
#define HSTRIDE 264
#define HBUF_N  (64 * HSTRIDE)
#define SSTRIDE 40
#define SBUF_N  (64 * SSTRIDE)    // 2560 per buffer

__global__ __launch_bounds__(1024)
void gru_kernel(const float* __restrict__ state,
                const __bf16* __restrict__ Wg1,  const __bf16* __restrict__ Win_n,
                const __bf16* __restrict__ Whh_n,
                const float* __restrict__ bhhn, __bf16* __restrict__ x0)
{
    __shared__ __bf16 hbuf[2 * HBUF_N];        // 67584 B
    __shared__ __bf16 sbuf[2 * SBUF_N];        // 10240 B; k 16..39 zero, k15 = 1.0
    __shared__ __bf16 rzbuf[4 * 1024 * 8];     // 65536 B: [nt][tid][8] r0..3|z0..3

    const int tid  = threadIdx.x;
    const int wave = tid >> 6;    // 0..15 : j-tile
    const int lane = tid & 63;
    const int q    = lane >> 4;
    const int ln   = lane & 15;
    const int b0   = blockIdx.x * 64;

    {   // zero h buffer 0 and both sbuf buffers
        bf16x8 z = {};
        bf16x8* p = (bf16x8*)hbuf;
        #pragma unroll 3
        for (int i = tid; i < HBUF_N / 8; i += 1024) p[i] = z;
        if (tid < 2 * SBUF_N / 8) ((bf16x8*)sbuf)[tid] = z;
    }
    const int srow = tid >> 4, sk = tid & 15;   // 64 rows x 16 cols staging

    // bhn (other biases folded into weight col 15 against sbuf's 1.0 column)
    const floatx4 Bhn = *(const floatx4*)(bhhn + wave * 16 + q * 4);

    const int jr = wave * 16 + ln;
    const __bf16* wr = Wg1   + (size_t)jr * 288 + q * 8;
    const __bf16* wz = Wg1   + (size_t)(256 + jr) * 288 + q * 8;
    const __bf16* wx = Win_n + (size_t)jr * 32  + q * 8;
    const __bf16* wh = Whh_n + (size_t)jr * 256 + q * 8;

    const __bf16* hread  = hbuf + ln * HSTRIDE + q * 8;              // + nt*16*HSTRIDE
    __bf16*       hwrite = hbuf + ln * HSTRIDE + wave * 16 + q * 4;  // + nt*16*HSTRIDE
    const __bf16* sread  = sbuf + ln * SSTRIDE + q * 8;              // + nt*16*SSTRIDE
    __bf16*       rzw    = rzbuf + tid * 8;                          // + nt*8192

    // stage state slice v=0, then set the permanent 1.0 bias column (k=15)
    if (sk < 15)
        sbuf[srow * SSTRIDE + sk] = (__bf16)state[(size_t)(b0 + srow) * 300 + sk];
    if (tid < 128) sbuf[(tid >> 6) * SBUF_N + (tid & 63) * SSTRIDE + 15] = (__bf16)1.0f;
    __syncthreads();

#define GRU_STEP(v, SB)                                                          \
    {                                                                            \
        float snext = 0.f;                                                       \
        if ((v) < 19 && sk < 15)                                                 \
            snext = state[(size_t)(b0 + srow) * 300 + ((v) + 1) * 15 + sk];      \
        _Pragma("unroll 1")                                                      \
        for (int p = 0; p < 2; ++p) {                                            \
            floatx4 acc0[4], acc1[4];                                            \
            const floatx4 zf = {0.f, 0.f, 0.f, 0.f};                             \
            _Pragma("unroll")                                                    \
            for (int nt = 0; nt < 4; nt++) { acc0[nt] = zf; acc1[nt] = zf; }     \
            if (p == 0) {                                                        \
                {                                                                \
                    bf16x8 a0 = *(const bf16x8*)(wr);                            \
                    bf16x8 a1 = *(const bf16x8*)(wz);                            \
                    _Pragma("unroll")                                            \
                    for (int nt = 0; nt < 4; nt++) {                             \
                        bf16x8 b = *(const bf16x8*)(sread + (SB) * SBUF_N +      \
                                                    nt * (16 * SSTRIDE));        \
                        acc0[nt] = MFMA16(a0, b, acc0[nt]);                      \
                        acc1[nt] = MFMA16(a1, b, acc1[nt]);                      \
                    }                                                            \
                }                                                                \
                _Pragma("unroll")                                                \
                for (int kk = 0; kk < 8; ++kk) {                                 \
                    bf16x8 a0 = *(const bf16x8*)(wr + 32 + kk * 32);             \
                    bf16x8 a1 = *(const bf16x8*)(wz + 32 + kk * 32);             \
                    _Pragma("unroll")                                            \
                    for (int nt = 0; nt < 4; nt++) {                             \
                        bf16x8 b = *(const bf16x8*)(hread + (SB) * HBUF_N +      \
                                                    nt * (16 * HSTRIDE) +        \
                                                    kk * 32);                    \
                        acc0[nt] = MFMA16(a0, b, acc0[nt]);                      \
                        acc1[nt] = MFMA16(a1, b, acc1[nt]);                      \
                    }                                                            \
                }                                                                \
                _Pragma("unroll")                                                \
                for (int nt = 0; nt < 4; nt++) {                                 \
                    bf16x8 rz;                                                   \
                    _Pragma("unroll")                                            \
                    for (int r = 0; r < 4; r++) {                                \
                        rz[r]     = (__bf16)sigmoid_f(acc0[nt][r]);              \
                        rz[4 + r] = (__bf16)sigmoid_f(acc1[nt][r]);              \
                    }                                                            \
                    *(bf16x8*)(rzw + nt * 8192) = rz;                            \
                }                                                                \
            } else {                                                             \
                {                                                                \
                    bf16x8 a0 = *(const bf16x8*)(wx);                            \
                    _Pragma("unroll")                                            \
                    for (int nt = 0; nt < 4; nt++) {                             \
                        bf16x8 b = *(const bf16x8*)(sread + (SB) * SBUF_N +      \
                                                    nt * (16 * SSTRIDE));        \
                        acc0[nt] = MFMA16(a0, b, acc0[nt]);                      \
                    }                                                            \
                }                                                                \
                _Pragma("unroll")                                                \
                for (int kk = 0; kk < 8; ++kk) {                                 \
                    bf16x8 a1 = *(const bf16x8*)(wh + kk * 32);                  \
                    _Pragma("unroll")                                            \
                    for (int nt = 0; nt < 4; nt++) {                             \
                        bf16x8 b = *(const bf16x8*)(hread + (SB) * HBUF_N +      \
                                                    nt * (16 * HSTRIDE) +        \
                                                    kk * 32);                    \
                        acc1[nt] = MFMA16(a1, b, acc1[nt]);                      \
                    }                                                            \
                }                                                                \
                _Pragma("unroll")                                                \
                for (int nt = 0; nt < 4; nt++) {                                 \
                    bf16x8 rz = *(const bf16x8*)(rzw + nt * 8192);               \
                    bf16x4 ho = *(const bf16x4*)(hwrite + (SB) * HBUF_N +        \
                                                 nt * (16 * HSTRIDE));           \
                    bf16x4 hv;                                                   \
                    _Pragma("unroll")                                            \
                    for (int r = 0; r < 4; r++) {                                \
                        float rg = (float)rz[r];                                 \
                        float zg = (float)rz[4 + r];                             \
                        float nn = tanh_f(acc0[nt][r] +                          \
                                          rg * (acc1[nt][r] + Bhn[r]));          \
                        float hnew = (1.f - zg) * nn + zg * (float)ho[r];        \
                        hv[r] = (__bf16)hnew;                                    \
                    }                                                            \
                    *(bf16x4*)(hwrite + (1 - (SB)) * HBUF_N +                    \
                               nt * (16 * HSTRIDE)) = hv;                        \
                }                                                                \
            }                                                                    \
        }                                                                        \
        if ((v) < 19 && sk < 15)                                                 \
            sbuf[(1 - (SB)) * SBUF_N + srow * SSTRIDE + sk] = (__bf16)snext;     \
        __syncthreads();                                                         \
    }

    #pragma unroll 1
    for (int v2 = 0; v2 < 10; ++v2) {
        GRU_STEP(2 * v2,     0)
        GRU_STEP(2 * v2 + 1, 1)
    }
#undef GRU_STEP

    // ---- epilogue: final h is in hbuf buffer 0 (step 19 wrote 1-SB = 0) ----
    // x0 = [state[:,0,:] (15) | 0-pad to 32 | h (256)], coalesced b128 moves.
    {
        const int erow = tid >> 4, p = tid & 15;
        #pragma unroll
        for (int s = 0; s < 2; s++) {
            const int col = p * 8 + s * 128;
            *(bf16x8*)(x0 + (size_t)(b0 + erow) * 288 + 32 + col) =
                *(const bf16x8*)(hbuf + erow * HSTRIDE + col);
        }
    }
    #pragma unroll
    for (int t = 0; t < 2; t++) {
        int i = tid + t * 1024;
        int erow = i >> 5, c = i & 31;
        float s = (c < 15) ? state[(size_t)(b0 + erow) * 300 + c] : 0.f;
        x0[(size_t)(b0 + erow) * 288 + c] = (__bf16)s;
    }
}

// ---------------------------------------------------------------------------
// LDS-staged GEMM, BK=64: C = act(A[M][K] @ W[N][K]^T + bias), bf16.
// 256 thr (4 waves 2x2), tile 128x128. Staging: 8 global_load_lds(16B)
// rounds per 64-k slab (two 32-k halves), ONE barrier pair per slab (halves
// r11's barrier count). K tail of 32 supported (gemm1 K=288).
// LDS: staging 32 KB inside the 34.8 KB bounce union.
// ---------------------------------------------------------------------------
__global__ __launch_bounds__(256)
void gemm_bias_act(const __bf16* __restrict__ A, const __bf16* __restrict__ W,
                   const float* __restrict__ bias, __bf16* __restrict__ C,
                   int N, int K, int relu)
{
    __shared__ __bf16 smem[128 * 136];           // 34816 B
    // staging layout: A-lo [128][32] @0, A-hi @4096, B-lo @8192, B-hi @12288

    const int tid  = threadIdx.x;
    const int wave = tid >> 6, lane = tid & 63;
    const int q = lane >> 4, ln = lane & 15;
    const int wm = wave >> 1, wn = wave & 1;
    const int arow0 = blockIdx.x * 128;
    const int bcol0 = blockIdx.y * 128;

    float bv[4];
    #pragma unroll
    for (int n = 0; n < 4; n++) bv[n] = bias[bcol0 + wn * 64 + n * 16 + ln];

    floatx4 acc[4][4];
    const floatx4 zf = {0.f, 0.f, 0.f, 0.f};
    #pragma unroll
    for (int m = 0; m < 4; m++)
        #pragma unroll
        for (int n = 0; n < 4; n++) acc[m][n] = zf;

    const int stg_row = wave * 16 + (lane >> 2);   // + rd*64
    const int stg_k   = (lane & 3) * 8;            // + h*32
    const int lds_off = wave * 512;                // + rd*2048, + h*4096

    int kt = 0;
    for (; kt + 64 <= K; kt += 64) {
        #pragma unroll
        for (int h = 0; h < 2; h++)
            #pragma unroll
            for (int rd = 0; rd < 2; rd++) {
                GL_LDS16(A + (size_t)(arow0 + stg_row + rd * 64) * K + kt + h * 32 + stg_k,
                         smem + h * 4096 + lds_off + rd * 2048);
                GL_LDS16(W + (size_t)(bcol0 + stg_row + rd * 64) * K + kt + h * 32 + stg_k,
                         smem + 8192 + h * 4096 + lds_off + rd * 2048);
            }
        __syncthreads();
        #pragma unroll
        for (int h = 0; h < 2; h++) {
            bf16x8 af[4], bf[4];
            #pragma unroll
            for (int m = 0; m < 4; m++)
                af[m] = *(const bf16x8*)(smem + h * 4096 + (wm * 64 + m * 16 + ln) * 32 + q * 8);
            #pragma unroll
            for (int n = 0; n < 4; n++)
                bf[n] = *(const bf16x8*)(smem + 8192 + h * 4096 + (wn * 64 + n * 16 + ln) * 32 + q * 8);
            #pragma unroll
            for (int n = 0; n < 4; n++)
                #pragma unroll
                for (int m = 0; m < 4; m++)
                    acc[m][n] = MFMA16(af[m], bf[n], acc[m][n]);
        }
        __syncthreads();
    }
    if (kt < K) {   // 32-k tail
        #pragma unroll
        for (int rd = 0; rd < 2; rd++) {
            GL_LDS16(A + (size_t)(arow0 + stg_row + rd * 64) * K + kt + stg_k,
                     smem + lds_off + rd * 2048);
            GL_LDS16(W + (size_t)(bcol0 + stg_row + rd * 64) * K + kt + stg_k,
                     smem + 8192 + lds_off + rd * 2048);
        }
        __syncthreads();
        bf16x8 af[4], bf[4];
        #pragma unroll
        for (int m = 0; m < 4; m++)
            af[m] = *(const bf16x8*)(smem + (wm * 64 + m * 16 + ln) * 32 + q * 8);
        #pragma unroll
        for (int n = 0; n < 4; n++)
            bf[n] = *(const bf16x8*)(smem + 8192 + (wn * 64 + n * 16 + ln) * 32 + q * 8);
        #pragma unroll
        for (int n = 0; n < 4; n++)
            #pragma unroll
            for (int m = 0; m < 4; m++)
                acc[m][n] = MFMA16(af[m], bf[n], acc[m][n]);
        __syncthreads();
    }

    // epilogue: bias+act -> LDS bounce (stride 136) -> coalesced b128 stores
    #pragma unroll
    for (int m = 0; m < 4; m++)
        #pragma unroll
        for (int n = 0; n < 4; n++)
            #pragma unroll
            for (int r = 0; r < 4; r++) {
                float val = acc[m][n][r] + bv[n];
                if (relu) val = fmaxf(val, 0.f);
                smem[(wm * 64 + m * 16 + q * 4 + r) * 136 + wn * 64 + n * 16 + ln] = (__bf16)val;
            }
    __syncthreads();
    {
        const int row = tid >> 4, seg = tid & 15;
        #pragma unroll
        for (int p = 0; p < 8; p++) {
            const int rr = row + p * 16;
            *(bf16x8*)(C + (size_t)(arow0 + rr) * N + bcol0 + seg * 8) =
                *(const bf16x8*)(smem + rr * 136 + seg * 8);
        }
    }
}

// ---------------------------------------------------------------------------
// Head: out[b] = tanh(dot(x4[b][0..255], Wp) + bp).  4 lanes per row.
// ---------------------------------------------------------------------------
__global__ __launch_bounds__(256)
void head_kernel(const __bf16* __restrict__ x4, const float* __restrict__ Wp,
                 const float* __restrict__ bp, float* __restrict__ out)
{
    const int tid = threadIdx.x;
    const int wave = tid >> 6, lane = tid & 63;
    const int row = blockIdx.x * 64 + wave * 16 + (lane >> 2);
    const int part = lane & 3;
    const __bf16* xp = x4 + (size_t)row * 256 + part * 64;
    const float* wp = Wp + part * 64;
    float sum = 0.f;
    #pragma unroll
    for (int i = 0; i < 8; i++) {
        bf16x8 xv = *(const bf16x8*)(xp + i * 8);
        #pragma unroll
        for (int jj = 0; jj < 8; jj++) sum += (float)xv[jj] * wp[i * 8 + jj];
    }
    sum += __shfl_xor(sum, 1);
    sum += __shfl_xor(sum, 2);
    if (part == 0) out[row] = tanhf(sum + bp[0]);
}

// ---------------------------------------------------------------------------
extern "C" void kernel_launch(void* const* d_in, const int* in_sizes, int n_in,
                              void* d_out, int out_size, void* d_ws, size_t ws_size,
                              hipStream_t stream)
{
    const float* state = (const float*)d_in[0];
    const float* W_ih  = (const float*)d_in[1];
    const float* W_hh  = (const float*)d_in[2];
    const float* b_ih  = (const float*)d_in[3];
    const float* b_hh  = (const float*)d_in[4];
    const float* W1    = (const float*)d_in[5];
    const float* b1    = (const float*)d_in[6];
    const float* W2    = (const float*)d_in[7];
    const float* b2    = (const float*)d_in[8];
    const float* W3    = (const float*)d_in[9];
    const float* b3    = (const float*)d_in[10];
    const float* W4    = (const float*)d_in[11];
    const float* b4    = (const float*)d_in[12];
    const float* Wp    = (const float*)d_in[13];
    const float* bp    = (const float*)d_in[14];
    float* out = (float*)d_out;

    char* ws = (char*)d_ws;
    size_t off = 0;
    auto alloc = [&](size_t bytes) -> void* {
        void* p = ws + off;
        off += (bytes + 255) & ~(size_t)255;
        return p;
    };
    __bf16* Wg1   = (__bf16*)alloc(512 * 288 * 2);
    __bf16* W1p   = (__bf16*)alloc(1024 * 288 * 2);
    __bf16* W2b   = (__bf16*)alloc(1024 * 1024 * 2);
    __bf16* W3b   = (__bf16*)alloc(512 * 1024 * 2);
    __bf16* W4b   = (__bf16*)alloc(256 * 512 * 2);
    __bf16* Win_n = (__bf16*)alloc(256 * 32 * 2);
    __bf16* Whh_n = (__bf16*)alloc(256 * 256 * 2);
    float*  bsum  = (float*)alloc(512 * 4);
    float*  bihn  = (float*)alloc(256 * 4);
    float*  bhhn  = (float*)alloc(256 * 4);
    __bf16* x0    = (__bf16*)alloc((size_t)16384 * 288 * 2);
    __bf16* xA    = (__bf16*)alloc((size_t)16384 * 1024 * 2);
    __bf16* xB    = (__bf16*)alloc((size_t)16384 * 1024 * 2);

    prep_kernel<<<2048, 256, 0, stream>>>(W_ih, W_hh, b_ih, b_hh, W1, W2, W3, W4,
                                          Wg1, W1p, W2b, W3b, W4b, Win_n, Whh_n,
                                          bsum, bihn, bhhn);
    gru_kernel<<<256, 1024, 0, stream>>>(state, Wg1, Win_n, Whh_n, bhhn, x0);
    gemm_bias_act<<<dim3(128, 8), 256, 0, stream>>>(x0, W1p, b1, xA, 1024, 288, 1);
    gemm_bias_act<<<dim3(128, 8), 256, 0, stream>>>(xA, W2b, b2, xB, 1024, 1024, 1);
    gemm_bias_act<<<dim3(128, 4), 256, 0, stream>>>(xB, W3b, b3, xA, 512, 1024, 1);
    gemm_bias_act<<<dim3(128, 2), 256, 0, stream>>>(xA, W4b, b4, xB, 256, 512, 1);
    head_kernel<<<256, 256, 0, stream>>>(xB, Wp, bp, out);
}

// Round 9
// 445.126 us; speedup vs baseline: 1.2283x; 1.0348x over previous
//
#include <hip/hip_runtime.h>

// ---------------------------------------------------------------------------
// Actor: GRU over V=20 vehicle slots (H=256) + MLP head 271->1024->1024->512->256->1
// B=16384, F=15. All GEMMs in bf16 MFMA (16x16x32), fp32 accumulate.
//
// Round-23: GRU untouched (r11 two-pass, verified local optimum: 292 us under
// the allocator laws -- arch-VGPR cap = 65536/wg_size; 64-row blocks
// mandatory for weight traffic; wg-1024/16-wave the only fit). This round
// attacks the non-GRU 168 us: the GEMM chain runs at ~440 TF effective
// because stage->barrier->compute->barrier never overlaps loads with MFMA
// inside a block. Rework gemm_bias_act to the T3 "minimum 2-phase" schedule:
// BK=32, double-buffered staging (2x16KB = 32KB, still under the 34.8KB
// bounce union -> occupancy unchanged at 4 blocks/CU), loads for slab k+1
// issued after the barrier and before compute(k), so the compiler's
// vmcnt(0)-at-barrier drain lands one compute-phase later. K%32==0 for all
// layers -> tail path deleted.
// ---------------------------------------------------------------------------

typedef __attribute__((ext_vector_type(8))) __bf16 bf16x8;
typedef __attribute__((ext_vector_type(4))) __bf16 bf16x4;
typedef __attribute__((ext_vector_type(4))) float  floatx4;

#define MFMA16(a, b, c) __builtin_amdgcn_mfma_f32_16x16x32_bf16((a), (b), (c), 0, 0, 0)

#define GL_LDS16(g, l)                                                         \
    __builtin_amdgcn_global_load_lds(                                          \
        (const __attribute__((address_space(1))) void*)(g),                    \
        (__attribute__((address_space(3))) void*)(l), 16, 0, 0)

__device__ __forceinline__ float sigmoid_f(float x) { return 1.f / (1.f + __expf(-x)); }
__device__ __forceinline__ float tanh_f(float x)    { return 1.f - 2.f / (1.f + __expf(2.f * x)); }

// ---------------------------------------------------------------------------
// Weight prep:
//   Wg1  [512][288]  rows g in {r(0..255), z(256..511)}:
//        [W_ih[g][0..14] | bsum[g] | 0 x16 | W_hh[g][0..255]]   (col 15 = bias)
//   W1p  [1024][288] : [W1[o][0..14] | 0 x17 | W1[o][15..270]]
//   W2b  [1024][1024], W3b [512][1024], W4b [256][512]  : direct cvt
//   Win_n[256][32]   : [W_ih[512+j][0..14] | b_ih[512+j] | 0 x16] (col 15 = bias)
//   Whh_n[256][256]  : W_hh rows 512..767
//   bhhn [256] = b_hh[512+]
// ---------------------------------------------------------------------------
#define S0 147456u
#define S1 442368u
#define S2 1490944u
#define S3 2015232u
#define S4 2146304u
#define S5 2154496u
#define S6 2220032u
#define S7 2220544u
#define S8 2221056u

__global__ void prep_kernel(const float* __restrict__ W_ih, const float* __restrict__ W_hh,
                            const float* __restrict__ b_ih, const float* __restrict__ b_hh,
                            const float* __restrict__ W1, const float* __restrict__ W2,
                            const float* __restrict__ W3, const float* __restrict__ W4,
                            __bf16* __restrict__ Wg1, __bf16* __restrict__ W1p,
                            __bf16* __restrict__ W2b, __bf16* __restrict__ W3b,
                            __bf16* __restrict__ W4b, __bf16* __restrict__ Win_n,
                            __bf16* __restrict__ Whh_n, float* __restrict__ bsum,
                            float* __restrict__ bihn, float* __restrict__ bhhn)
{
    for (unsigned i = blockIdx.x * blockDim.x + threadIdx.x; i < S8; i += gridDim.x * blockDim.x) {
        if (i < S0) {
            unsigned g = i / 288u, c = i % 288u;
            float v;
            if (c < 15u)       v = W_ih[g * 15u + c];
            else if (c == 15u) v = b_ih[g] + b_hh[g];          // folded r/z bias
            else if (c < 32u)  v = 0.f;
            else               v = W_hh[g * 256u + (c - 32u)];
            Wg1[i] = (__bf16)v;
        } else if (i < S1) {
            unsigned t = i - S0, o = t / 288u, c = t % 288u;
            float v = (c < 15u) ? W1[o * 271u + c] : ((c < 32u) ? 0.f : W1[o * 271u + (c - 17u)]);
            W1p[t] = (__bf16)v;
        } else if (i < S2) {
            unsigned t = i - S1; W2b[t] = (__bf16)W2[t];
        } else if (i < S3) {
            unsigned t = i - S2; W3b[t] = (__bf16)W3[t];
        } else if (i < S4) {
            unsigned t = i - S3; W4b[t] = (__bf16)W4[t];
        } else if (i < S5) {
            unsigned t = i - S4, j = t / 32u, c = t % 32u;
            float v;
            if (c < 15u)       v = W_ih[(512u + j) * 15u + c];
            else if (c == 15u) v = b_ih[512u + j];             // folded xn bias
            else               v = 0.f;
            Win_n[t] = (__bf16)v;
        } else if (i < S6) {
            unsigned t = i - S5; Whh_n[t] = (__bf16)W_hh[512u * 256u + t];
        } else if (i < S7) {
            unsigned t = i - S6; bsum[t] = b_ih[t] + b_hh[t];
        } else {
            unsigned t = i - S7;
            if (t < 256u) bihn[t] = b_ih[512u + t];
            else          bhhn[t - 256u] = b_hh[512u + t - 256u];
        }
    }
}

// ---------------------------------------------------------------------------
// GRU kernel (r11, UNCHANGED). 256 blocks x 1024 threads (16 waves). 64 batch
// rows/block. Wave w owns gate cols w*16..w*16+15. Per step, 2 unroll-1
// passes:
//   p0: acc (ar,az) over all 4 nt (32 regs) -> sigmoid -> rzbuf[nt][tid]
//   p1: acc (axn,ahn) (32 regs) -> n=tanh(axn+r*(ahn+bhn)), h'=(1-z)n+z*h_old
// hbuf[2][64][264] double-buffered, 1 barrier/step. sbuf stride 40:
// 5*ln+q mod 8 covers all 8 bank groups -> conflict-free state reads.
// ---------------------------------------------------------------------------
#define HSTRIDE 264
#define HBUF_N  (64 * HSTRIDE)
#define SSTRIDE 40
#define SBUF_N  (64 * SSTRIDE)    // 2560 per buffer

__global__ __launch_bounds__(1024)
void gru_kernel(const float* __restrict__ state,
                const __bf16* __restrict__ Wg1,  const __bf16* __restrict__ Win_n,
                const __bf16* __restrict__ Whh_n,
                const float* __restrict__ bhhn, __bf16* __restrict__ x0)
{
    __shared__ __bf16 hbuf[2 * HBUF_N];        // 67584 B
    __shared__ __bf16 sbuf[2 * SBUF_N];        // 10240 B; k 16..39 zero, k15 = 1.0
    __shared__ __bf16 rzbuf[4 * 1024 * 8];     // 65536 B: [nt][tid][8] r0..3|z0..3

    const int tid  = threadIdx.x;
    const int wave = tid >> 6;    // 0..15 : j-tile
    const int lane = tid & 63;
    const int q    = lane >> 4;
    const int ln   = lane & 15;
    const int b0   = blockIdx.x * 64;

    {   // zero h buffer 0 and both sbuf buffers
        bf16x8 z = {};
        bf16x8* p = (bf16x8*)hbuf;
        #pragma unroll 3
        for (int i = tid; i < HBUF_N / 8; i += 1024) p[i] = z;
        if (tid < 2 * SBUF_N / 8) ((bf16x8*)sbuf)[tid] = z;
    }
    const int srow = tid >> 4, sk = tid & 15;   // 64 rows x 16 cols staging

    // bhn (other biases folded into weight col 15 against sbuf's 1.0 column)
    const floatx4 Bhn = *(const floatx4*)(bhhn + wave * 16 + q * 4);

    const int jr = wave * 16 + ln;
    const __bf16* wr = Wg1   + (size_t)jr * 288 + q * 8;
    const __bf16* wz = Wg1   + (size_t)(256 + jr) * 288 + q * 8;
    const __bf16* wx = Win_n + (size_t)jr * 32  + q * 8;
    const __bf16* wh = Whh_n + (size_t)jr * 256 + q * 8;

    const __bf16* hread  = hbuf + ln * HSTRIDE + q * 8;              // + nt*16*HSTRIDE
    __bf16*       hwrite = hbuf + ln * HSTRIDE + wave * 16 + q * 4;  // + nt*16*HSTRIDE
    const __bf16* sread  = sbuf + ln * SSTRIDE + q * 8;              // + nt*16*SSTRIDE
    __bf16*       rzw    = rzbuf + tid * 8;                          // + nt*8192

    // stage state slice v=0, then set the permanent 1.0 bias column (k=15)
    if (sk < 15)
        sbuf[srow * SSTRIDE + sk] = (__bf16)state[(size_t)(b0 + srow) * 300 + sk];
    if (tid < 128) sbuf[(tid >> 6) * SBUF_N + (tid & 63) * SSTRIDE + 15] = (__bf16)1.0f;
    __syncthreads();

#define GRU_STEP(v, SB)                                                          \
    {                                                                            \
        float snext = 0.f;                                                       \
        if ((v) < 19 && sk < 15)                                                 \
            snext = state[(size_t)(b0 + srow) * 300 + ((v) + 1) * 15 + sk];      \
        _Pragma("unroll 1")                                                      \
        for (int p = 0; p < 2; ++p) {                                            \
            floatx4 acc0[4], acc1[4];                                            \
            const floatx4 zf = {0.f, 0.f, 0.f, 0.f};                             \
            _Pragma("unroll")                                                    \
            for (int nt = 0; nt < 4; nt++) { acc0[nt] = zf; acc1[nt] = zf; }     \
            if (p == 0) {                                                        \
                {                                                                \
                    bf16x8 a0 = *(const bf16x8*)(wr);                            \
                    bf16x8 a1 = *(const bf16x8*)(wz);                            \
                    _Pragma("unroll")                                            \
                    for (int nt = 0; nt < 4; nt++) {                             \
                        bf16x8 b = *(const bf16x8*)(sread + (SB) * SBUF_N +      \
                                                    nt * (16 * SSTRIDE));        \
                        acc0[nt] = MFMA16(a0, b, acc0[nt]);                      \
                        acc1[nt] = MFMA16(a1, b, acc1[nt]);                      \
                    }                                                            \
                }                                                                \
                _Pragma("unroll")                                                \
                for (int kk = 0; kk < 8; ++kk) {                                 \
                    bf16x8 a0 = *(const bf16x8*)(wr + 32 + kk * 32);             \
                    bf16x8 a1 = *(const bf16x8*)(wz + 32 + kk * 32);             \
                    _Pragma("unroll")                                            \
                    for (int nt = 0; nt < 4; nt++) {                             \
                        bf16x8 b = *(const bf16x8*)(hread + (SB) * HBUF_N +      \
                                                    nt * (16 * HSTRIDE) +        \
                                                    kk * 32);                    \
                        acc0[nt] = MFMA16(a0, b, acc0[nt]);                      \
                        acc1[nt] = MFMA16(a1, b, acc1[nt]);                      \
                    }                                                            \
                }                                                                \
                _Pragma("unroll")                                                \
                for (int nt = 0; nt < 4; nt++) {                                 \
                    bf16x8 rz;                                                   \
                    _Pragma("unroll")                                            \
                    for (int r = 0; r < 4; r++) {                                \
                        rz[r]     = (__bf16)sigmoid_f(acc0[nt][r]);              \
                        rz[4 + r] = (__bf16)sigmoid_f(acc1[nt][r]);              \
                    }                                                            \
                    *(bf16x8*)(rzw + nt * 8192) = rz;                            \
                }                                                                \
            } else {                                                             \
                {                                                                \
                    bf16x8 a0 = *(const bf16x8*)(wx);                            \
                    _Pragma("unroll")                                            \
                    for (int nt = 0; nt < 4; nt++) {                             \
                        bf16x8 b = *(const bf16x8*)(sread + (SB) * SBUF_N +      \
                                                    nt * (16 * SSTRIDE));        \
                        acc0[nt] = MFMA16(a0, b, acc0[nt]);                      \
                    }                                                            \
                }                                                                \
                _Pragma("unroll")                                                \
                for (int kk = 0; kk < 8; ++kk) {                                 \
                    bf16x8 a1 = *(const bf16x8*)(wh + kk * 32);                  \
                    _Pragma("unroll")                                            \
                    for (int nt = 0; nt < 4; nt++) {                             \
                        bf16x8 b = *(const bf16x8*)(hread + (SB) * HBUF_N +      \
                                                    nt * (16 * HSTRIDE) +        \
                                                    kk * 32);                    \
                        acc1[nt] = MFMA16(a1, b, acc1[nt]);                      \
                    }                                                            \
                }                                                                \
                _Pragma("unroll")                                                \
                for (int nt = 0; nt < 4; nt++) {                                 \
                    bf16x8 rz = *(const bf16x8*)(rzw + nt * 8192);               \
                    bf16x4 ho = *(const bf16x4*)(hwrite + (SB) * HBUF_N +        \
                                                 nt * (16 * HSTRIDE));           \
                    bf16x4 hv;                                                   \
                    _Pragma("unroll")                                            \
                    for (int r = 0; r < 4; r++) {                                \
                        float rg = (float)rz[r];                                 \
                        float zg = (float)rz[4 + r];                             \
                        float nn = tanh_f(acc0[nt][r] +                          \
                                          rg * (acc1[nt][r] + Bhn[r]));          \
                        float hnew = (1.f - zg) * nn + zg * (float)ho[r];        \
                        hv[r] = (__bf16)hnew;                                    \
                    }                                                            \
                    *(bf16x4*)(hwrite + (1 - (SB)) * HBUF_N +                    \
                               nt * (16 * HSTRIDE)) = hv;                        \
                }                                                                \
            }                                                                    \
        }                                                                        \
        if ((v) < 19 && sk < 15)                                                 \
            sbuf[(1 - (SB)) * SBUF_N + srow * SSTRIDE + sk] = (__bf16)snext;     \
        __syncthreads();                                                         \
    }

    #pragma unroll 1
    for (int v2 = 0; v2 < 10; ++v2) {
        GRU_STEP(2 * v2,     0)
        GRU_STEP(2 * v2 + 1, 1)
    }
#undef GRU_STEP

    // ---- epilogue: final h is in hbuf buffer 0 (step 19 wrote 1-SB = 0) ----
    // x0 = [state[:,0,:] (15) | 0-pad to 32 | h (256)], coalesced b128 moves.
    {
        const int erow = tid >> 4, p = tid & 15;
        #pragma unroll
        for (int s = 0; s < 2; s++) {
            const int col = p * 8 + s * 128;
            *(bf16x8*)(x0 + (size_t)(b0 + erow) * 288 + 32 + col) =
                *(const bf16x8*)(hbuf + erow * HSTRIDE + col);
        }
    }
    #pragma unroll
    for (int t = 0; t < 2; t++) {
        int i = tid + t * 1024;
        int erow = i >> 5, c = i & 31;
        float s = (c < 15) ? state[(size_t)(b0 + erow) * 300 + c] : 0.f;
        x0[(size_t)(b0 + erow) * 288 + c] = (__bf16)s;
    }
}

// ---------------------------------------------------------------------------
// LDS-staged GEMM, BK=32 double-buffered (T3 minimum 2-phase):
// C = act(A[M][K] @ W[N][K]^T + bias), bf16. 256 thr (4 waves 2x2), tile
// 128x128. Per slab: 4 global_load_lds(16B)/thread issued AFTER the barrier
// and BEFORE compute of the previous slab -> the compiler's vmcnt(0) drain
// at the next barrier lands one compute-phase later (loads overlap MFMA).
// Staging 2 x (A 8KB + B 8KB) = 32KB inside the 34.8KB bounce union ->
// occupancy unchanged (4 blocks/CU). K%32==0 for all layers (288/1024/512).
// ---------------------------------------------------------------------------
__global__ __launch_bounds__(256)
void gemm_bias_act(const __bf16* __restrict__ A, const __bf16* __restrict__ W,
                   const float* __restrict__ bias, __bf16* __restrict__ C,
                   int N, int K, int relu)
{
    __shared__ __bf16 smem[128 * 136];           // 34816 B (bounce; staging in first 32KB)
    // staging (bf16 units): buf0 A @0, B @4096; buf1 A @8192, B @12288

    const int tid  = threadIdx.x;
    const int wave = tid >> 6, lane = tid & 63;
    const int q = lane >> 4, ln = lane & 15;
    const int wm = wave >> 1, wn = wave & 1;
    const int arow0 = blockIdx.x * 128;
    const int bcol0 = blockIdx.y * 128;

    float bv[4];
    #pragma unroll
    for (int n = 0; n < 4; n++) bv[n] = bias[bcol0 + wn * 64 + n * 16 + ln];

    floatx4 acc[4][4];
    const floatx4 zf = {0.f, 0.f, 0.f, 0.f};
    #pragma unroll
    for (int m = 0; m < 4; m++)
        #pragma unroll
        for (int n = 0; n < 4; n++) acc[m][n] = zf;

    const int stg_row = wave * 16 + (lane >> 2);   // + rd*64
    const int stg_k   = (lane & 3) * 8;
    const int lds_off = wave * 512;                // + rd*2048

#define STAGE(kt, b)                                                            \
    {                                                                           \
        _Pragma("unroll")                                                       \
        for (int rd = 0; rd < 2; rd++) {                                        \
            GL_LDS16(A + (size_t)(arow0 + stg_row + rd * 64) * K + (kt) * 32 + stg_k, \
                     smem + (b) * 8192 + lds_off + rd * 2048);                  \
            GL_LDS16(W + (size_t)(bcol0 + stg_row + rd * 64) * K + (kt) * 32 + stg_k, \
                     smem + 4096 + (b) * 8192 + lds_off + rd * 2048);           \
        }                                                                       \
    }

#define GCOMPUTE(b)                                                             \
    {                                                                           \
        bf16x8 af[4], bf[4];                                                    \
        _Pragma("unroll")                                                       \
        for (int m = 0; m < 4; m++)                                             \
            af[m] = *(const bf16x8*)(smem + (b) * 8192 +                        \
                                     (wm * 64 + m * 16 + ln) * 32 + q * 8);     \
        _Pragma("unroll")                                                       \
        for (int n = 0; n < 4; n++)                                             \
            bf[n] = *(const bf16x8*)(smem + 4096 + (b) * 8192 +                 \
                                     (wn * 64 + n * 16 + ln) * 32 + q * 8);     \
        _Pragma("unroll")                                                       \
        for (int n = 0; n < 4; n++)                                             \
            _Pragma("unroll")                                                   \
            for (int m = 0; m < 4; m++)                                         \
                acc[m][n] = MFMA16(af[m], bf[n], acc[m][n]);                    \
    }

    const int nk = K >> 5;          // K multiple of 32 for all layers
    STAGE(0, 0)
    int kt = 0;
    #pragma unroll 1
    for (; kt + 2 <= nk; kt += 2) {
        __syncthreads();                 // buf0 slab ready; buf1 free
        if (kt + 1 < nk) STAGE(kt + 1, 1)
        GCOMPUTE(0)                      // compute slab kt while kt+1 loads fly
        __syncthreads();                 // buf1 slab ready; buf0 free
        if (kt + 2 < nk) STAGE(kt + 2, 0)
        GCOMPUTE(1)                      // compute slab kt+1 while kt+2 loads fly
    }
    if (kt < nk) {                       // odd slab count (gemm1: nk=9)
        __syncthreads();
        GCOMPUTE(0)
    }
    __syncthreads();                     // staging reads done -> bounce may reuse
#undef STAGE
#undef GCOMPUTE

    // epilogue: bias+act -> LDS bounce (stride 136) -> coalesced b128 stores
    #pragma unroll
    for (int m = 0; m < 4; m++)
        #pragma unroll
        for (int n = 0; n < 4; n++)
            #pragma unroll
            for (int r = 0; r < 4; r++) {
                float val = acc[m][n][r] + bv[n];
                if (relu) val = fmaxf(val, 0.f);
                smem[(wm * 64 + m * 16 + q * 4 + r) * 136 + wn * 64 + n * 16 + ln] = (__bf16)val;
            }
    __syncthreads();
    {
        const int row = tid >> 4, seg = tid & 15;
        #pragma unroll
        for (int p = 0; p < 8; p++) {
            const int rr = row + p * 16;
            *(bf16x8*)(C + (size_t)(arow0 + rr) * N + bcol0 + seg * 8) =
                *(const bf16x8*)(smem + rr * 136 + seg * 8);
        }
    }
}

// ---------------------------------------------------------------------------
// Head: out[b] = tanh(dot(x4[b][0..255], Wp) + bp).  4 lanes per row.
// ---------------------------------------------------------------------------
__global__ __launch_bounds__(256)
void head_kernel(const __bf16* __restrict__ x4, const float* __restrict__ Wp,
                 const float* __restrict__ bp, float* __restrict__ out)
{
    const int tid = threadIdx.x;
    const int wave = tid >> 6, lane = tid & 63;
    const int row = blockIdx.x * 64 + wave * 16 + (lane >> 2);
    const int part = lane & 3;
    const __bf16* xp = x4 + (size_t)row * 256 + part * 64;
    const float* wp = Wp + part * 64;
    float sum = 0.f;
    #pragma unroll
    for (int i = 0; i < 8; i++) {
        bf16x8 xv = *(const bf16x8*)(xp + i * 8);
        #pragma unroll
        for (int jj = 0; jj < 8; jj++) sum += (float)xv[jj] * wp[i * 8 + jj];
    }
    sum += __shfl_xor(sum, 1);
    sum += __shfl_xor(sum, 2);
    if (part == 0) out[row] = tanhf(sum + bp[0]);
}

// ---------------------------------------------------------------------------
extern "C" void kernel_launch(void* const* d_in, const int* in_sizes, int n_in,
                              void* d_out, int out_size, void* d_ws, size_t ws_size,
                              hipStream_t stream)
{
    const float* state = (const float*)d_in[0];
    const float* W_ih  = (const float*)d_in[1];
    const float* W_hh  = (const float*)d_in[2];
    const float* b_ih  = (const float*)d_in[3];
    const float* b_hh  = (const float*)d_in[4];
    const float* W1    = (const float*)d_in[5];
    const float* b1    = (const float*)d_in[6];
    const float* W2    = (const float*)d_in[7];
    const float* b2    = (const float*)d_in[8];
    const float* W3    = (const float*)d_in[9];
    const float* b3    = (const float*)d_in[10];
    const float* W4    = (const float*)d_in[11];
    const float* b4    = (const float*)d_in[12];
    const float* Wp    = (const float*)d_in[13];
    const float* bp    = (const float*)d_in[14];
    float* out = (float*)d_out;

    char* ws = (char*)d_ws;
    size_t off = 0;
    auto alloc = [&](size_t bytes) -> void* {
        void* p = ws + off;
        off += (bytes + 255) & ~(size_t)255;
        return p;
    };
    __bf16* Wg1   = (__bf16*)alloc(512 * 288 * 2);
    __bf16* W1p   = (__bf16*)alloc(1024 * 288 * 2);
    __bf16* W2b   = (__bf16*)alloc(1024 * 1024 * 2);
    __bf16* W3b   = (__bf16*)alloc(512 * 1024 * 2);
    __bf16* W4b   = (__bf16*)alloc(256 * 512 * 2);
    __bf16* Win_n = (__bf16*)alloc(256 * 32 * 2);
    __bf16* Whh_n = (__bf16*)alloc(256 * 256 * 2);
    float*  bsum  = (float*)alloc(512 * 4);
    float*  bihn  = (float*)alloc(256 * 4);
    float*  bhhn  = (float*)alloc(256 * 4);
    __bf16* x0    = (__bf16*)alloc((size_t)16384 * 288 * 2);
    __bf16* xA    = (__bf16*)alloc((size_t)16384 * 1024 * 2);
    __bf16* xB    = (__bf16*)alloc((size_t)16384 * 1024 * 2);

    prep_kernel<<<2048, 256, 0, stream>>>(W_ih, W_hh, b_ih, b_hh, W1, W2, W3, W4,
                                          Wg1, W1p, W2b, W3b, W4b, Win_n, Whh_n,
                                          bsum, bihn, bhhn);
    gru_kernel<<<256, 1024, 0, stream>>>(state, Wg1, Win_n, Whh_n, bhhn, x0);
    gemm_bias_act<<<dim3(128, 8), 256, 0, stream>>>(x0, W1p, b1, xA, 1024, 288, 1);
    gemm_bias_act<<<dim3(128, 8), 256, 0, stream>>>(xA, W2b, b2, xB, 1024, 1024, 1);
    gemm_bias_act<<<dim3(128, 4), 256, 0, stream>>>(xB, W3b, b3, xA, 512, 1024, 1);
    gemm_bias_act<<<dim3(128, 2), 256, 0, stream>>>(xA, W4b, b4, xB, 256, 512, 1);
    head_kernel<<<256, 256, 0, stream>>>(xB, Wp, bp, out);
}